// Round 1
// baseline (992.465 us; speedup 1.0000x reference)
//
#include <hip/hip_runtime.h>
#include <math.h>

#define T_DIM 2048
#define N_DIM 64
#define E_DIM 1024
#define A_DIM 256

// ---------------- d_proj[n][a] = dot(dec_h[n,:], W_d[a,:]) ----------------
__global__ __launch_bounds__(256) void dproj_kernel(
    const float* __restrict__ dec_h, const float* __restrict__ W_d,
    float* __restrict__ d_proj) {
    __shared__ float dec[E_DIM];
    const int n = blockIdx.x;
    const int tid = threadIdx.x;  // 256
    reinterpret_cast<float4*>(dec)[tid] =
        reinterpret_cast<const float4*>(dec_h + (size_t)n * E_DIM)[tid];
    __syncthreads();
    const int a = tid;
    const float* w = W_d + (size_t)a * E_DIM;
    float acc = 0.f;
#pragma unroll 4
    for (int e = 0; e < E_DIM; e += 4) {
        float4 wv = *reinterpret_cast<const float4*>(w + e);
        acc = fmaf(wv.x, dec[e], acc);
        acc = fmaf(wv.y, dec[e + 1], acc);
        acc = fmaf(wv.z, dec[e + 2], acc);
        acc = fmaf(wv.w, dec[e + 3], acc);
    }
    d_proj[n * A_DIM + a] = acc;
}

// ---- scores[m] = sum_a v[a]*tanh( sum_e enc[m,e]*W_e[a,e] + d_proj[m%64,a] )
// GEMM tile: BM=128 rows x 256 cols (full A dim), BK=16, 512 threads.
#define BM 128
#define BK 16
__global__ __launch_bounds__(512, 2) void scores_kernel(
    const float* __restrict__ enc, const float* __restrict__ W_e,
    const float* __restrict__ d_proj, const float* __restrict__ v,
    float* __restrict__ scores) {
    __shared__ float At[BK][BM];     // 8 KB, transposed: At[k][row]
    __shared__ float Bt[BK][A_DIM];  // 16 KB, transposed: Bt[k][a]

    const int tid = threadIdx.x;
    const int m0 = blockIdx.x * BM;
    const int tm = tid >> 5;  // 0..15 -> rows tm*8..tm*8+7
    const int tn = tid & 31;  // 0..31 -> cols tn*8..tn*8+7

    float acc[8][8];
#pragma unroll
    for (int i = 0; i < 8; ++i)
#pragma unroll
        for (int j = 0; j < 8; ++j) acc[i][j] = 0.f;

    const int ar = tid >> 2;  // 0..127 A-tile row
    const int ac = tid & 3;   // quad within row

    for (int k0 = 0; k0 < E_DIM; k0 += BK) {
        // stage A tile (128 x 16), transposed into LDS
        float4 av = *reinterpret_cast<const float4*>(
            enc + (size_t)(m0 + ar) * E_DIM + k0 + ac * 4);
        At[ac * 4 + 0][ar] = av.x;
        At[ac * 4 + 1][ar] = av.y;
        At[ac * 4 + 2][ar] = av.z;
        At[ac * 4 + 3][ar] = av.w;
        // stage B tile (256 x 16), transposed
#pragma unroll
        for (int j = 0; j < 2; ++j) {
            int idx = tid + j * 512;
            int br = idx >> 2;  // 0..255
            int bc = idx & 3;
            float4 bv = *reinterpret_cast<const float4*>(
                W_e + (size_t)br * E_DIM + k0 + bc * 4);
            Bt[bc * 4 + 0][br] = bv.x;
            Bt[bc * 4 + 1][br] = bv.y;
            Bt[bc * 4 + 2][br] = bv.z;
            Bt[bc * 4 + 3][br] = bv.w;
        }
        __syncthreads();
#pragma unroll
        for (int k = 0; k < BK; ++k) {
            float a8[8], b8[8];
            *reinterpret_cast<float4*>(a8) =
                *reinterpret_cast<const float4*>(&At[k][tm * 8]);
            *reinterpret_cast<float4*>(a8 + 4) =
                *reinterpret_cast<const float4*>(&At[k][tm * 8 + 4]);
            *reinterpret_cast<float4*>(b8) =
                *reinterpret_cast<const float4*>(&Bt[k][tn * 8]);
            *reinterpret_cast<float4*>(b8 + 4) =
                *reinterpret_cast<const float4*>(&Bt[k][tn * 8 + 4]);
#pragma unroll
            for (int i = 0; i < 8; ++i)
#pragma unroll
                for (int j = 0; j < 8; ++j)
                    acc[i][j] = fmaf(a8[i], b8[j], acc[i][j]);
        }
        __syncthreads();
    }

    // epilogue: tanh + dot with v, reduce over the 32 tn-threads per row
#pragma unroll
    for (int i = 0; i < 8; ++i) {
        const int mloc = tm * 8 + i;
        const int n = (m0 + mloc) & (N_DIM - 1);
        float partial = 0.f;
#pragma unroll
        for (int j = 0; j < 8; ++j) {
            const int a = tn * 8 + j;
            partial = fmaf(v[a], tanhf(acc[i][j] + d_proj[n * A_DIM + a]),
                           partial);
        }
#pragma unroll
        for (int off = 16; off; off >>= 1) partial += __shfl_xor(partial, off);
        if (tn == 0) scores[m0 + mloc] = partial;
    }
}

// ---------------- softmax over t per column n ----------------
__global__ __launch_bounds__(256) void softmax_kernel(
    const float* __restrict__ scores, float* __restrict__ alpha) {
    __shared__ float red[256];
    const int n = blockIdx.x;
    const int tid = threadIdx.x;
    float m = -3.4e38f;
    for (int t = tid; t < T_DIM; t += 256)
        m = fmaxf(m, scores[t * N_DIM + n]);
    red[tid] = m;
    __syncthreads();
    for (int s = 128; s; s >>= 1) {
        if (tid < s) red[tid] = fmaxf(red[tid], red[tid + s]);
        __syncthreads();
    }
    m = red[0];
    __syncthreads();
    float sum = 0.f;
    for (int t = tid; t < T_DIM; t += 256)
        sum += expf(scores[t * N_DIM + n] - m);
    red[tid] = sum;
    __syncthreads();
    for (int s = 128; s; s >>= 1) {
        if (tid < s) red[tid] += red[tid + s];
        __syncthreads();
    }
    const float inv = 1.f / red[0];
    for (int t = tid; t < T_DIM; t += 256)
        alpha[t * N_DIM + n] = expf(scores[t * N_DIM + n] - m) * inv;
}

// ---------------- ctx partials: out[chunk][n][e] = sum_{t in chunk} ----------
__global__ __launch_bounds__(256) void ctx_partial_kernel(
    const float* __restrict__ enc, const float* __restrict__ alpha,
    float* __restrict__ out, int tlen) {
    const int n = blockIdx.x;   // 64
    const int tc = blockIdx.y;  // chunks
    const int tid = threadIdx.x;
    float4 acc = {0.f, 0.f, 0.f, 0.f};
    const int t0 = tc * tlen;
    for (int t = t0; t < t0 + tlen; ++t) {
        const float al = alpha[t * N_DIM + n];
        float4 ev = *reinterpret_cast<const float4*>(
            enc + (size_t)(t * N_DIM + n) * E_DIM + tid * 4);
        acc.x = fmaf(al, ev.x, acc.x);
        acc.y = fmaf(al, ev.y, acc.y);
        acc.z = fmaf(al, ev.z, acc.z);
        acc.w = fmaf(al, ev.w, acc.w);
    }
    *reinterpret_cast<float4*>(out + ((size_t)tc * N_DIM + n) * E_DIM +
                               tid * 4) = acc;
}

__global__ __launch_bounds__(256) void ctx_reduce_kernel(
    const float* __restrict__ partial, float* __restrict__ ctx, int nchunk) {
    const int idx = blockIdx.x * 256 + threadIdx.x;  // over 64*1024
    float s = 0.f;
    for (int c = 0; c < nchunk; ++c) s += partial[(size_t)c * 65536 + idx];
    ctx[idx] = s;
}

extern "C" void kernel_launch(void* const* d_in, const int* in_sizes, int n_in,
                              void* d_out, int out_size, void* d_ws,
                              size_t ws_size, hipStream_t stream) {
    const float* enc = (const float*)d_in[0];    // [T,N,E]
    const float* dec_h = (const float*)d_in[1];  // [N,D]
    const float* W_e = (const float*)d_in[2];    // [A,E]
    const float* W_d = (const float*)d_in[3];    // [A,D]
    const float* v = (const float*)d_in[4];      // [1,A]

    float* out = (float*)d_out;
    float* ctx = out;                // 64*1024
    float* alpha = out + 65536;      // 2048*64

    float* ws = (float*)d_ws;
    float* d_proj = ws;                      // 16384 floats
    float* scores = ws + 16384;              // 131072 floats
    float* partial = ws + 16384 + 131072;    // up to 524288 floats

    dproj_kernel<<<N_DIM, 256, 0, stream>>>(dec_h, W_d, d_proj);
    scores_kernel<<<(T_DIM * N_DIM) / BM, 512, 0, stream>>>(enc, W_e, d_proj,
                                                            v, scores);
    softmax_kernel<<<N_DIM, 256, 0, stream>>>(scores, alpha);

    const size_t need8 = (size_t)(16384 + 131072 + 8 * 65536) * sizeof(float);
    if (ws_size >= need8) {
        dim3 g(N_DIM, 8);
        ctx_partial_kernel<<<g, 256, 0, stream>>>(enc, alpha, partial,
                                                  T_DIM / 8);
        ctx_reduce_kernel<<<256, 256, 0, stream>>>(partial, ctx, 8);
    } else {
        dim3 g(N_DIM, 1);
        ctx_partial_kernel<<<g, 256, 0, stream>>>(enc, alpha, ctx, T_DIM);
    }
}

// Round 2
// 314.265 us; speedup vs baseline: 3.1580x; 3.1580x over previous
//
#include <hip/hip_runtime.h>
#include <math.h>

#define T_DIM 2048
#define N_DIM 64
#define E_DIM 1024
#define A_DIM 256

typedef __bf16 bf16x8 __attribute__((ext_vector_type(8)));
typedef float f32x4 __attribute__((ext_vector_type(4)));

__device__ __forceinline__ float tanh_fast(float x) {
    float xc = fminf(fmaxf(x, -15.f), 15.f);
    float e = __expf(2.f * xc);
    return (e - 1.f) / (e + 1.f);
}

// ---- W_e fp32 [A,E] -> bf16, permuted so scores-kernel B staging is linear:
// unit (kt,g,a) holds W_e[a][kt*32+g*8 .. +8] at offset ((kt*4+g)*256+a)*8
__global__ __launch_bounds__(256) void convert_W(const float* __restrict__ W_e,
                                                 __bf16* __restrict__ Wp) {
    const int uid = blockIdx.x * 256 + threadIdx.x;  // 32768 units
    const int a = uid >> 7;
    const int c = uid & 127;  // c = kt*4+g
    const float4* src = (const float4*)(W_e + (size_t)a * E_DIM + c * 8);
    float4 x0 = src[0], x1 = src[1];
    bf16x8 o;
    o[0] = (__bf16)x0.x; o[1] = (__bf16)x0.y; o[2] = (__bf16)x0.z; o[3] = (__bf16)x0.w;
    o[4] = (__bf16)x1.x; o[5] = (__bf16)x1.y; o[6] = (__bf16)x1.z; o[7] = (__bf16)x1.w;
    *(bf16x8*)(Wp + ((size_t)c * 256 + a) * 8) = o;
}

// ---------------- d_proj[n][a] = dot(dec_h[n,:], W_d[a,:]) ----------------
__global__ __launch_bounds__(256) void dproj_kernel(
    const float* __restrict__ dec_h, const float* __restrict__ W_d,
    float* __restrict__ d_proj) {
    __shared__ float dec[E_DIM];
    const int n = blockIdx.x;
    const int tid = threadIdx.x;
    reinterpret_cast<float4*>(dec)[tid] =
        reinterpret_cast<const float4*>(dec_h + (size_t)n * E_DIM)[tid];
    __syncthreads();
    const float* w = W_d + (size_t)tid * E_DIM;
    float acc = 0.f;
#pragma unroll 4
    for (int e = 0; e < E_DIM; e += 4) {
        float4 wv = *reinterpret_cast<const float4*>(w + e);
        acc = fmaf(wv.x, dec[e], acc);
        acc = fmaf(wv.y, dec[e + 1], acc);
        acc = fmaf(wv.z, dec[e + 2], acc);
        acc = fmaf(wv.w, dec[e + 3], acc);
    }
    d_proj[n * A_DIM + tid] = acc;
}

// ---- fused: e_proj = enc @ W_e^T (bf16 MFMA), tanh(+dproj), dot v ----
// BM=256 rows x A_DIM=256 cols, BK=32, 512 threads = 8 waves (2x4),
// wave tile 128x64 = 8x4 fragments of 16x16. Double-buffered LDS.
__global__ __launch_bounds__(512) void scores_mfma(
    const float* __restrict__ enc, const __bf16* __restrict__ Wp,
    const float* __restrict__ dproj, const float* __restrict__ v,
    float* __restrict__ scores) {
    __shared__ __bf16 Ab[2][4 * 256 * 8];  // 2 x 16 KB  [g][row][8]
    __shared__ __bf16 Bb[2][4 * 256 * 8];  // 2 x 16 KB  [g][a][8]
    __shared__ float vs_[A_DIM];

    const int tid = threadIdx.x;
    const int m0 = blockIdx.x * 256;
    const int wid = tid >> 6, lane = tid & 63;
    const int wm = wid >> 2, wn = wid & 3;
    const int lr = lane & 15, lg = lane >> 4;

    if (tid < A_DIM) vs_[tid] = v[tid];

    f32x4 acc[8][4];
#pragma unroll
    for (int i = 0; i < 8; ++i)
#pragma unroll
        for (int j = 0; j < 4; ++j) acc[i][j] = (f32x4){0.f, 0.f, 0.f, 0.f};

    const int arow = tid >> 2;  // 0..127 ; second unit row = arow+128
    const int ag = tid & 3;
    const float* encA0 = enc + (size_t)(m0 + arow) * E_DIM + ag * 8;
    const float* encA1 = enc + (size_t)(m0 + arow + 128) * E_DIM + ag * 8;

    // prologue: stage kt=0 into buffer 0
    {
        float4 a0 = *(const float4*)(encA0);
        float4 a1 = *(const float4*)(encA0 + 4);
        float4 a2 = *(const float4*)(encA1);
        float4 a3 = *(const float4*)(encA1 + 4);
        bf16x8 b0 = ((const bf16x8*)Wp)[tid];
        bf16x8 b1 = ((const bf16x8*)Wp)[tid + 512];
        bf16x8 p0, p1;
        p0[0] = (__bf16)a0.x; p0[1] = (__bf16)a0.y; p0[2] = (__bf16)a0.z; p0[3] = (__bf16)a0.w;
        p0[4] = (__bf16)a1.x; p0[5] = (__bf16)a1.y; p0[6] = (__bf16)a1.z; p0[7] = (__bf16)a1.w;
        p1[0] = (__bf16)a2.x; p1[1] = (__bf16)a2.y; p1[2] = (__bf16)a2.z; p1[3] = (__bf16)a2.w;
        p1[4] = (__bf16)a3.x; p1[5] = (__bf16)a3.y; p1[6] = (__bf16)a3.z; p1[7] = (__bf16)a3.w;
        ((bf16x8*)Ab[0])[ag * 256 + arow] = p0;
        ((bf16x8*)Ab[0])[ag * 256 + arow + 128] = p1;
        ((bf16x8*)Bb[0])[tid] = b0;
        ((bf16x8*)Bb[0])[tid + 512] = b1;
    }
    __syncthreads();

    float4 aR0, aR1, aR2, aR3;
    bf16x8 bR0, bR1;
    for (int kt = 0; kt < 32; ++kt) {
        const int cur = kt & 1;
        if (kt < 31) {  // issue next-tile global loads early (hide under MFMA)
            const int k = (kt + 1) * 32;
            aR0 = *(const float4*)(encA0 + k);
            aR1 = *(const float4*)(encA0 + k + 4);
            aR2 = *(const float4*)(encA1 + k);
            aR3 = *(const float4*)(encA1 + k + 4);
            bR0 = ((const bf16x8*)Wp)[(size_t)(kt + 1) * 1024 + tid];
            bR1 = ((const bf16x8*)Wp)[(size_t)(kt + 1) * 1024 + tid + 512];
        }
        const bf16x8* As = (const bf16x8*)Ab[cur];
        const bf16x8* Bs = (const bf16x8*)Bb[cur];
        bf16x8 bf[4];
#pragma unroll
        for (int fn = 0; fn < 4; ++fn)
            bf[fn] = Bs[lg * 256 + wn * 64 + fn * 16 + lr];
#pragma unroll
        for (int fm = 0; fm < 8; ++fm) {
            bf16x8 af = As[lg * 256 + wm * 128 + fm * 16 + lr];
#pragma unroll
            for (int fn = 0; fn < 4; ++fn)
                acc[fm][fn] = __builtin_amdgcn_mfma_f32_16x16x32_bf16(
                    af, bf[fn], acc[fm][fn], 0, 0, 0);
        }
        __syncthreads();  // all reads of buf[cur] done
        if (kt < 31) {    // write-late into the other buffer
            bf16x8 p0, p1;
            p0[0] = (__bf16)aR0.x; p0[1] = (__bf16)aR0.y; p0[2] = (__bf16)aR0.z; p0[3] = (__bf16)aR0.w;
            p0[4] = (__bf16)aR1.x; p0[5] = (__bf16)aR1.y; p0[6] = (__bf16)aR1.z; p0[7] = (__bf16)aR1.w;
            p1[0] = (__bf16)aR2.x; p1[1] = (__bf16)aR2.y; p1[2] = (__bf16)aR2.z; p1[3] = (__bf16)aR2.w;
            p1[4] = (__bf16)aR3.x; p1[5] = (__bf16)aR3.y; p1[6] = (__bf16)aR3.z; p1[7] = (__bf16)aR3.w;
            bf16x8* An = (bf16x8*)Ab[cur ^ 1];
            bf16x8* Bn = (bf16x8*)Bb[cur ^ 1];
            An[ag * 256 + arow] = p0;
            An[ag * 256 + arow + 128] = p1;
            Bn[tid] = bR0;
            Bn[tid + 512] = bR1;
        }
        __syncthreads();  // writes visible for next iteration
    }

    // ---- epilogue: tanh(e+d) dot v, reduce over a ----
    float* red = (float*)Ab[0];  // 4*256 floats, overlays LDS (safe: barriered)
#pragma unroll
    for (int fm = 0; fm < 8; ++fm) {
#pragma unroll
        for (int reg = 0; reg < 4; ++reg) {
            const int r = wm * 128 + fm * 16 + lg * 4 + reg;
            const int n = r & 63;  // m0 is a multiple of 64
            float p = 0.f;
#pragma unroll
            for (int fn = 0; fn < 4; ++fn) {
                const int a = wn * 64 + fn * 16 + lr;
                float x = acc[fm][fn][reg] + dproj[n * A_DIM + a];
                p = fmaf(vs_[a], tanh_fast(x), p);
            }
            p += __shfl_xor(p, 1);
            p += __shfl_xor(p, 2);
            p += __shfl_xor(p, 4);
            p += __shfl_xor(p, 8);
            if (lr == 0) red[wn * 256 + r] = p;
        }
    }
    __syncthreads();
    if (tid < 256)
        scores[m0 + tid] =
            red[tid] + red[256 + tid] + red[512 + tid] + red[768 + tid];
}

// ---------------- softmax over t per column n ----------------
__global__ __launch_bounds__(256) void softmax_kernel(
    const float* __restrict__ scores, float* __restrict__ alpha) {
    __shared__ float red[256];
    const int n = blockIdx.x;
    const int tid = threadIdx.x;
    float m = -3.4e38f;
    for (int t = tid; t < T_DIM; t += 256)
        m = fmaxf(m, scores[t * N_DIM + n]);
    red[tid] = m;
    __syncthreads();
    for (int s = 128; s; s >>= 1) {
        if (tid < s) red[tid] = fmaxf(red[tid], red[tid + s]);
        __syncthreads();
    }
    m = red[0];
    __syncthreads();
    float sum = 0.f;
    for (int t = tid; t < T_DIM; t += 256)
        sum += expf(scores[t * N_DIM + n] - m);
    red[tid] = sum;
    __syncthreads();
    for (int s = 128; s; s >>= 1) {
        if (tid < s) red[tid] += red[tid + s];
        __syncthreads();
    }
    const float inv = 1.f / red[0];
    for (int t = tid; t < T_DIM; t += 256)
        alpha[t * N_DIM + n] = expf(scores[t * N_DIM + n] - m) * inv;
}

// ---------------- ctx partials ----------------
__global__ __launch_bounds__(256) void ctx_partial_kernel(
    const float* __restrict__ enc, const float* __restrict__ alpha,
    float* __restrict__ out, int tlen) {
    const int n = blockIdx.x;
    const int tc = blockIdx.y;
    const int tid = threadIdx.x;
    float4 acc = {0.f, 0.f, 0.f, 0.f};
    const int t0 = tc * tlen;
#pragma unroll 4
    for (int t = t0; t < t0 + tlen; ++t) {
        const float al = alpha[t * N_DIM + n];
        float4 ev = *reinterpret_cast<const float4*>(
            enc + (size_t)(t * N_DIM + n) * E_DIM + tid * 4);
        acc.x = fmaf(al, ev.x, acc.x);
        acc.y = fmaf(al, ev.y, acc.y);
        acc.z = fmaf(al, ev.z, acc.z);
        acc.w = fmaf(al, ev.w, acc.w);
    }
    *reinterpret_cast<float4*>(out + ((size_t)tc * N_DIM + n) * E_DIM +
                               tid * 4) = acc;
}

__global__ __launch_bounds__(256) void ctx_reduce_kernel(
    const float* __restrict__ partial, float* __restrict__ ctx, int nchunk) {
    const int idx = blockIdx.x * 256 + threadIdx.x;
    float s = 0.f;
    for (int c = 0; c < nchunk; ++c) s += partial[(size_t)c * 65536 + idx];
    ctx[idx] = s;
}

extern "C" void kernel_launch(void* const* d_in, const int* in_sizes, int n_in,
                              void* d_out, int out_size, void* d_ws,
                              size_t ws_size, hipStream_t stream) {
    const float* enc = (const float*)d_in[0];    // [T,N,E]
    const float* dec_h = (const float*)d_in[1];  // [N,D]
    const float* W_e = (const float*)d_in[2];    // [A,E]
    const float* W_d = (const float*)d_in[3];    // [A,D]
    const float* v = (const float*)d_in[4];      // [1,A]

    float* out = (float*)d_out;
    float* ctx = out;            // 64*1024
    float* alpha = out + 65536;  // 2048*64

    float* ws = (float*)d_ws;
    float* d_proj = ws;           // 16384 floats
    float* scores = ws + 16384;   // 131072 floats
    __bf16* Wp = (__bf16*)(ws + 147456);   // 262144 bf16 = 131072 floats
    float* partial = ws + 147456;          // overlays Wp (used after scores)

    convert_W<<<128, 256, 0, stream>>>(W_e, Wp);
    dproj_kernel<<<N_DIM, 256, 0, stream>>>(dec_h, W_d, d_proj);
    scores_mfma<<<512, 512, 0, stream>>>(enc, Wp, d_proj, v, scores);
    softmax_kernel<<<N_DIM, 256, 0, stream>>>(scores, alpha);

    const size_t need8 = (size_t)(147456 + 8 * 65536) * sizeof(float);
    if (ws_size >= need8) {
        dim3 g(N_DIM, 8);
        ctx_partial_kernel<<<g, 256, 0, stream>>>(enc, alpha, partial,
                                                  T_DIM / 8);
        ctx_reduce_kernel<<<256, 256, 0, stream>>>(partial, ctx, 8);
    } else {
        dim3 g(N_DIM, 1);
        ctx_partial_kernel<<<g, 256, 0, stream>>>(enc, alpha, ctx, T_DIM);
    }
}